// Round 9
// baseline (165.009 us; speedup 1.0000x reference)
//
#include <hip/hip_runtime.h>

#define EMB 16
#define BSH 7                 // 128 right-nodes per bucket
#define BNODES 128
#define MAXNB 1024
#define PCHUNK 4096           // small chunks -> 782 blocks -> latency hiding
#define REC_CAP 5120          // records sorted per LDS tile (40 KB)
typedef unsigned int u32;
typedef unsigned long long u64;

__global__ void zero_f32(float* __restrict__ p, size_t n) {
    size_t i = (size_t)blockIdx.x * blockDim.x + threadIdx.x;
    size_t stride = (size_t)gridDim.x * blockDim.x;
    for (; i < n; i += stride) p[i] = 0.0f;
}

__global__ void zero_i32(int* __restrict__ p, int n) {
    int i = blockIdx.x * blockDim.x + threadIdx.x;
    if (i < n) p[i] = 0;
}

__device__ __forceinline__ u32 bf16bits_rne(float x) {
    u32 u = __float_as_uint(x);
    return (u + 0x7fffu + ((u >> 16) & 1u)) >> 16;
}

// Packed bf16 linear: Y[row*8+h] = pack(bf16(row@W[:,h+8]+b), bf16(row@W[:,h]+b))
__global__ void linear16_pack_kernel(const float* __restrict__ X, const float* __restrict__ W,
                                     const float* __restrict__ b, u32* __restrict__ Y, int N) {
    int tid = blockIdx.x * blockDim.x + threadIdx.x;
    int row = tid >> 3;
    int h = tid & 7;
    if (row >= N) return;
    float a0 = b ? b[h] : 0.0f;
    float a1 = b ? b[h + 8] : 0.0f;
    const float* xr = X + (size_t)row * EMB;
#pragma unroll
    for (int k = 0; k < EMB; ++k) {
        float xv = xr[k];
        a0 = fmaf(xv, W[k * EMB + h], a0);
        a1 = fmaf(xv, W[k * EMB + h + 8], a1);
    }
    Y[(size_t)row * 8 + h] = (bf16bits_rne(a1) << 16) | bf16bits_rne(a0);
}

// Plain f32 linear (fallback path)
__global__ void linear16_kernel(const float* __restrict__ X, const float* __restrict__ W,
                                const float* __restrict__ b, float* __restrict__ Y, int N) {
    int tid = blockIdx.x * blockDim.x + threadIdx.x;
    int row = tid >> 4;
    int j = tid & 15;
    if (row >= N) return;
    float acc = b ? b[j] : 0.0f;
    const float* xr = X + (size_t)row * EMB;
#pragma unroll
    for (int k = 0; k < EMB; ++k) acc = fmaf(xr[k], W[k * EMB + j], acc);
    Y[(size_t)row * EMB + j] = acc;
}

// ---------------- bucket CSR build ----------------

__global__ void bucket_hist_kernel(const int* __restrict__ ridx, int* __restrict__ bhist,
                                   int E, int NB) {
    __shared__ int h[MAXNB];
    int t = threadIdx.x;
    for (int i = t; i < NB; i += 256) h[i] = 0;
    __syncthreads();
    int idx = blockIdx.x * blockDim.x + t;
    int stride = gridDim.x * blockDim.x;
    for (int e = idx; e < E; e += stride) atomicAdd(&h[ridx[e] >> BSH], 1);
    __syncthreads();
    for (int i = t; i < NB; i += 256) if (h[i]) atomicAdd(&bhist[i], h[i]);
}

__global__ void bucket_scan_kernel(const int* __restrict__ bhist, int* __restrict__ boff,
                                   int* __restrict__ gcur, int NB) {
    __shared__ int sc[1024];
    int t = threadIdx.x;
    int v = (t < NB) ? bhist[t] : 0;
    sc[t] = v;
    __syncthreads();
    for (int d = 1; d < 1024; d <<= 1) {
        int x = (t >= d) ? sc[t - d] : 0;
        __syncthreads();
        sc[t] += x;
        __syncthreads();
    }
    int excl = sc[t] - v;
    if (t < NB) { boff[t] = excl; gcur[t] = excl; }
    if (t == 1023) boff[NB] = sc[1023];
}

// Two-pass partition: LDS hist -> one aggregated global reservation per bucket
// -> clustered scatter of packed records [f:32][l:24][rl:7].
// 256 threads / 4K-edge chunks / 8KB LDS -> many blocks per CU (latency hiding).
__launch_bounds__(256)
__global__ void partition_kernel(const int* __restrict__ eidx, const float* __restrict__ ef,
                                 int* __restrict__ gcur, u64* __restrict__ rec, int E, int NB) {
    __shared__ int hist[MAXNB];
    __shared__ int lbase[MAXNB];
    int t = threadIdx.x;
    long long base = (long long)blockIdx.x * PCHUNK;
    int n = (int)((E - base) < PCHUNK ? (E - base) : PCHUNK);
    const int* ridx = eidx + E;
    for (int i = t; i < NB; i += 256) hist[i] = 0;
    __syncthreads();
    for (int i = t; i < n; i += 256) atomicAdd(&hist[ridx[base + i] >> BSH], 1);
    __syncthreads();
    for (int i = t; i < NB; i += 256) {
        int h = hist[i];
        lbase[i] = h ? atomicAdd(&gcur[i], h) : 0;
        hist[i] = 0;  // reuse as local cursor
    }
    __syncthreads();
    for (int i = t; i < n; i += 256) {
        int r = ridx[base + i];
        int b = r >> BSH;
        int l = eidx[base + i];
        float f = ef[base + i];
        int pos = lbase[b] + atomicAdd(&hist[b], 1);
        rec[pos] = ((u64)__float_as_uint(f) << 32) | ((u64)(u32)l << BSH) | (u32)(r & (BNODES - 1));
    }
}

// ---------------- gather: one block per 128-node bucket ----------------
// In-block counting sort by local node id (int LDS atomics only), then
// owner-computes: 4 threads per node accumulate in REGISTERS (zero fp atomics),
// combine via shfl_xor, coalesced float4 store of S.
__launch_bounds__(512)
__global__ void bucket_gather_kernel(const u64* __restrict__ rec, const int* __restrict__ boff,
                                     const u32* __restrict__ Lpk, const u32* __restrict__ Rpk,
                                     const float* __restrict__ We,
                                     float* __restrict__ S, int* __restrict__ deg, int n_right) {
    __shared__ u64 srec[REC_CAP];                        // 40 KB sorted records
    __shared__ int hist[BNODES], sc[BNODES], base_[BNODES], cur[BNODES];
    int b = blockIdx.x;
    int t = threadIdx.x;
    int node0 = b << BSH;
    int start = boff[b], end = boff[b + 1];

    int n = t >> 2, q = t & 3;        // owner: node n (0..127), slice q (0..3)
    int node = node0 + n;
    bool nv = node < n_right;

    float we[16];
#pragma unroll
    for (int j = 0; j < 16; ++j) we[j] = We[j];

    float rv[16];
    if (nv) {
        const uint4* rp = (const uint4*)(Rpk + (size_t)node * 8);
        uint4 ra = rp[0], rb = rp[1];
        u32 w0 = ra.x, w1 = ra.y, w2 = ra.z, w3 = ra.w;
        u32 w4 = rb.x, w5 = rb.y, w6 = rb.z, w7 = rb.w;
        rv[0] = __uint_as_float(w0 << 16); rv[8]  = __uint_as_float(w0 & 0xffff0000u);
        rv[1] = __uint_as_float(w1 << 16); rv[9]  = __uint_as_float(w1 & 0xffff0000u);
        rv[2] = __uint_as_float(w2 << 16); rv[10] = __uint_as_float(w2 & 0xffff0000u);
        rv[3] = __uint_as_float(w3 << 16); rv[11] = __uint_as_float(w3 & 0xffff0000u);
        rv[4] = __uint_as_float(w4 << 16); rv[12] = __uint_as_float(w4 & 0xffff0000u);
        rv[5] = __uint_as_float(w5 << 16); rv[13] = __uint_as_float(w5 & 0xffff0000u);
        rv[6] = __uint_as_float(w6 << 16); rv[14] = __uint_as_float(w6 & 0xffff0000u);
        rv[7] = __uint_as_float(w7 << 16); rv[15] = __uint_as_float(w7 & 0xffff0000u);
    } else {
#pragma unroll
        for (int j = 0; j < 16; ++j) rv[j] = 0.0f;
    }

    float acc[16];
#pragma unroll
    for (int j = 0; j < 16; ++j) acc[j] = 0.0f;
    int dsum = 0;

    for (int tile = start; tile < end; tile += REC_CAP) {
        int m = end - tile; if (m > REC_CAP) m = REC_CAP;
        for (int i = t; i < BNODES; i += 512) hist[i] = 0;
        __syncthreads();
        // pass 1: per-node count (int LDS atomics)
        for (int i = t; i < m; i += 512) {
            u64 rc = rec[tile + i];
            atomicAdd(&hist[(int)(rc & (u32)(BNODES - 1))], 1);
        }
        __syncthreads();
        // exclusive scan over 128 counts (Hillis-Steele, uniform barriers)
        if (t < BNODES) sc[t] = hist[t];
        __syncthreads();
        for (int d = 1; d < BNODES; d <<= 1) {
            int v = 0;
            if (t < BNODES && t >= d) v = sc[t - d];
            __syncthreads();
            if (t < BNODES && t >= d) sc[t] += v;
            __syncthreads();
        }
        if (t < BNODES) { int e0 = sc[t] - hist[t]; base_[t] = e0; cur[t] = e0; }
        __syncthreads();
        // pass 2: scatter records into sorted LDS positions (int LDS atomics)
        for (int i = t; i < m; i += 512) {
            u64 rc = rec[tile + i];
            int pos = atomicAdd(&cur[(int)(rc & (u32)(BNODES - 1))], 1);
            srec[pos] = rc;
        }
        __syncthreads();
        // owner phase: node n's slice-q thread walks its run, register accumulate
        {
            int c  = nv ? hist[n] : 0;
            int b0 = nv ? base_[n] : 0;
            if (q == 0) dsum += c;
            for (int k = q; k < c; k += 4) {
                u64 rc = srec[b0 + k];
                int l = (int)((rc >> BSH) & 0xFFFFFFu);
                float f = __uint_as_float((u32)(rc >> 32));
                const uint4* lp = (const uint4*)(Lpk + (size_t)l * 8);
                uint4 la = lp[0], lb = lp[1];
                u32 w0 = la.x, w1 = la.y, w2 = la.z, w3 = la.w;
                u32 w4 = lb.x, w5 = lb.y, w6 = lb.z, w7 = lb.w;
#define PAIR(h, lw) { \
                float l0 = __uint_as_float(lw << 16); \
                float l1 = __uint_as_float(lw & 0xffff0000u); \
                acc[h]     += fmaxf(fmaf(f, we[h], l0) + rv[h], 0.0f); \
                acc[h + 8] += fmaxf(fmaf(f, we[h + 8], l1) + rv[h + 8], 0.0f); }
                PAIR(0, w0) PAIR(1, w1) PAIR(2, w2) PAIR(3, w3)
                PAIR(4, w4) PAIR(5, w5) PAIR(6, w6) PAIR(7, w7)
#undef PAIR
            }
        }
        __syncthreads();  // before hist/srec reuse in next tile
    }

    // combine the 4 owner slices (lanes 4n..4n+3 are in the same wave)
#pragma unroll
    for (int j = 0; j < 16; ++j) {
        acc[j] += __shfl_xor(acc[j], 1, 64);
        acc[j] += __shfl_xor(acc[j], 2, 64);
    }
    if (nv) {
        float4 o = make_float4(acc[q * 4], acc[q * 4 + 1], acc[q * 4 + 2], acc[q * 4 + 3]);
        ((float4*)(S + (size_t)node * EMB))[q] = o;
        if (q == 0) deg[node] = dsum;
    }
}

// ---------------- fallback atomic edge kernel (f32 tables) ----------------
__global__ void edge_kernel(const int* __restrict__ eidx, const float* __restrict__ ef,
                            const float* __restrict__ L, const float* __restrict__ R,
                            const float* __restrict__ We, float* __restrict__ S,
                            int* __restrict__ cnt, int E) {
    long long tid = (long long)blockIdx.x * blockDim.x + threadIdx.x;
    int e = (int)(tid >> 4);
    int j = (int)(tid & 15);
    if (e >= E) return;
    int l = eidx[e];
    int r = eidx[E + e];
    float v = L[(size_t)l * EMB + j] + ef[e] * We[j] + R[(size_t)r * EMB + j];
    v = fmaxf(v, 0.0f);
    unsafeAtomicAdd(&S[(size_t)r * EMB + j], v);
    if (j == 0) atomicAdd(&cnt[r], 1);
}

// ---------------- per-node epilogue ----------------
__global__ void final_kernel(const float* __restrict__ S, const int* __restrict__ deg,
                             const float* __restrict__ rf,
                             const float* __restrict__ Wf, const float* __restrict__ bf,
                             const float* __restrict__ Wp, const float* __restrict__ bp,
                             const float* __restrict__ Wo1, const float* __restrict__ bo1,
                             const float* __restrict__ Wo2, const float* __restrict__ bo2,
                             float* __restrict__ out, int N) {
    __shared__ float sWf[256], sWp[256], sWo1[512], sWo2[256];
    __shared__ float sb[64];
    int t = threadIdx.x;
    for (int i = t; i < 256; i += 256) { sWf[i] = Wf[i]; sWp[i] = Wp[i]; sWo2[i] = Wo2[i]; }
    for (int i = t; i < 512; i += 256) sWo1[i] = Wo1[i];
    if (t < 16) { sb[t] = bf[t]; sb[16 + t] = bp[t]; sb[32 + t] = bo1[t]; sb[48 + t] = bo2[t]; }
    __syncthreads();

    int r = blockIdx.x * blockDim.x + t;
    if (r >= N) return;

    float s[16], x[16], y[16], rv[16], z[16], o[16];
    const float4* Sp = (const float4*)(S + (size_t)r * EMB);
    const float4* Rp = (const float4*)(rf + (size_t)r * EMB);
#pragma unroll
    for (int k = 0; k < 4; ++k) {
        float4 v = Sp[k];
        s[4 * k] = v.x; s[4 * k + 1] = v.y; s[4 * k + 2] = v.z; s[4 * k + 3] = v.w;
        float4 w = Rp[k];
        rv[4 * k] = w.x; rv[4 * k + 1] = w.y; rv[4 * k + 2] = w.z; rv[4 * k + 3] = w.w;
    }
    float c = (float)deg[r];

#pragma unroll
    for (int j = 0; j < 16; ++j) {
        float a = c * sb[j];
#pragma unroll
        for (int k = 0; k < 16; ++k) a = fmaf(s[k], sWf[k * 16 + j], a);
        x[j] = fmaxf(a, 0.0f);
    }
#pragma unroll
    for (int j = 0; j < 16; ++j) {
        float a = sb[16 + j];
#pragma unroll
        for (int k = 0; k < 16; ++k) a = fmaf(x[k], sWp[k * 16 + j], a);
        y[j] = a;
    }
#pragma unroll
    for (int j = 0; j < 16; ++j) {
        float a = sb[32 + j];
#pragma unroll
        for (int k = 0; k < 16; ++k) a = fmaf(y[k], sWo1[k * 16 + j], a);
#pragma unroll
        for (int k = 0; k < 16; ++k) a = fmaf(rv[k], sWo1[(16 + k) * 16 + j], a);
        z[j] = fmaxf(a, 0.0f);
    }
#pragma unroll
    for (int j = 0; j < 16; ++j) {
        float a = sb[48 + j];
#pragma unroll
        for (int k = 0; k < 16; ++k) a = fmaf(z[k], sWo2[k * 16 + j], a);
        o[j] = a;
    }
    float4* Op = (float4*)(out + (size_t)r * EMB);
#pragma unroll
    for (int k = 0; k < 4; ++k)
        Op[k] = make_float4(o[4 * k], o[4 * k + 1], o[4 * k + 2], o[4 * k + 3]);
}

extern "C" void kernel_launch(void* const* d_in, const int* in_sizes, int n_in,
                              void* d_out, int out_size, void* d_ws, size_t ws_size,
                              hipStream_t stream) {
    const float* lf     = (const float*)d_in[0];
    const int*   eidx   = (const int*)d_in[1];
    const float* ef     = (const float*)d_in[2];
    const float* rf     = (const float*)d_in[3];
    const float* W_left = (const float*)d_in[4];
    const float* b_left = (const float*)d_in[5];
    const float* W_edge = (const float*)d_in[6];
    const float* W_right= (const float*)d_in[7];
    const float* W_final= (const float*)d_in[8];
    const float* b_final= (const float*)d_in[9];
    const float* W_post = (const float*)d_in[10];
    const float* b_post = (const float*)d_in[11];
    const float* W_out1 = (const float*)d_in[12];
    const float* b_out1 = (const float*)d_in[13];
    const float* W_out2 = (const float*)d_in[14];
    const float* b_out2 = (const float*)d_in[15];

    int n_left  = in_sizes[0] / EMB;
    int E       = in_sizes[2];
    int n_right = in_sizes[3] / EMB;
    float* out = (float*)d_out;

    int NB = (n_right + BNODES - 1) >> BSH;

    size_t need = (size_t)E * 8
                + ((size_t)n_left + (size_t)n_right) * 8 * 4   // Lpk, Rpk
                + (size_t)n_right * EMB * 4                    // S
                + (size_t)n_right * 4                          // deg
                + (size_t)(3 * MAXNB + 2) * 4;

    if (ws_size >= need && NB <= MAXNB) {
        u64* rec   = (u64*)d_ws;
        u32* Lpk   = (u32*)(rec + (size_t)E);
        u32* Rpk   = Lpk + (size_t)n_left * 8;
        float* S   = (float*)(Rpk + (size_t)n_right * 8);
        int* deg   = (int*)(S + (size_t)n_right * EMB);
        int* bhist = deg + n_right;
        int* boff  = bhist + MAXNB;      // NB+1 entries
        int* gcur  = boff + MAXNB + 1;

        zero_i32<<<(NB + 255) / 256, 256, 0, stream>>>(bhist, NB);
        linear16_pack_kernel<<<(n_left * 8 + 255) / 256, 256, 0, stream>>>(lf, W_left, b_left, Lpk, n_left);
        linear16_pack_kernel<<<(n_right * 8 + 255) / 256, 256, 0, stream>>>(rf, W_right, nullptr, Rpk, n_right);

        bucket_hist_kernel<<<512, 256, 0, stream>>>(eidx + E, bhist, E, NB);
        bucket_scan_kernel<<<1, 1024, 0, stream>>>(bhist, boff, gcur, NB);

        int nchunks = (E + PCHUNK - 1) / PCHUNK;
        partition_kernel<<<nchunks, 256, 0, stream>>>(eidx, ef, gcur, rec, E, NB);

        bucket_gather_kernel<<<NB, 512, 0, stream>>>(rec, boff, Lpk, Rpk, W_edge, S, deg, n_right);

        final_kernel<<<(n_right + 255) / 256, 256, 0, stream>>>(S, deg, rf,
            W_final, b_final, W_post, b_post, W_out1, b_out1, W_out2, b_out2, out, n_right);
    } else {
        float* L   = (float*)d_ws;
        float* R   = L + (size_t)n_left * EMB;
        float* S   = R + (size_t)n_right * EMB;
        int*   cnt = (int*)(S + (size_t)n_right * EMB);

        zero_f32<<<2048, 256, 0, stream>>>(S, (size_t)n_right * EMB);
        zero_i32<<<(n_right + 255) / 256, 256, 0, stream>>>(cnt, n_right);

        linear16_kernel<<<(n_left * EMB + 255) / 256, 256, 0, stream>>>(lf, W_left, b_left, L, n_left);
        linear16_kernel<<<(n_right * EMB + 255) / 256, 256, 0, stream>>>(rf, W_right, nullptr, R, n_right);

        long long ethreads = (long long)E * EMB;
        edge_kernel<<<(unsigned)((ethreads + 255) / 256), 256, 0, stream>>>(eidx, ef, L, R, W_edge, S, cnt, E);

        final_kernel<<<(n_right + 255) / 256, 256, 0, stream>>>(S, cnt, rf,
            W_final, b_final, W_post, b_post, W_out1, b_out1, W_out2, b_out2, out, n_right);
    }
}

// Round 10
// 128.261 us; speedup vs baseline: 1.2865x; 1.2865x over previous
//
#include <hip/hip_runtime.h>

#define EMB 16
#define BSH 8                 // 256 right-nodes per bucket
#define BNODES 256
#define MAXNB 512
#define PCHUNK 8192           // edges per partition block
#define REC_CAP 5120          // records sorted per LDS tile in gather (40 KB)
typedef unsigned int u32;
typedef unsigned long long u64;

__global__ void zero_f32(float* __restrict__ p, size_t n) {
    size_t i = (size_t)blockIdx.x * blockDim.x + threadIdx.x;
    size_t stride = (size_t)gridDim.x * blockDim.x;
    for (; i < n; i += stride) p[i] = 0.0f;
}

__global__ void zero_i32(int* __restrict__ p, int n) {
    int i = blockIdx.x * blockDim.x + threadIdx.x;
    if (i < n) p[i] = 0;
}

__device__ __forceinline__ u32 bf16bits_rne(float x) {
    u32 u = __float_as_uint(x);
    return (u + 0x7fffu + ((u >> 16) & 1u)) >> 16;
}

// Packed bf16 linear: Y[row*8+h] = pack(bf16(row@W[:,h+8]+b), bf16(row@W[:,h]+b))
__global__ void linear16_pack_kernel(const float* __restrict__ X, const float* __restrict__ W,
                                     const float* __restrict__ b, u32* __restrict__ Y, int N) {
    int tid = blockIdx.x * blockDim.x + threadIdx.x;
    int row = tid >> 3;
    int h = tid & 7;
    if (row >= N) return;
    float a0 = b ? b[h] : 0.0f;
    float a1 = b ? b[h + 8] : 0.0f;
    const float* xr = X + (size_t)row * EMB;
#pragma unroll
    for (int k = 0; k < EMB; ++k) {
        float xv = xr[k];
        a0 = fmaf(xv, W[k * EMB + h], a0);
        a1 = fmaf(xv, W[k * EMB + h + 8], a1);
    }
    Y[(size_t)row * 8 + h] = (bf16bits_rne(a1) << 16) | bf16bits_rne(a0);
}

// Plain f32 linear (fallback path)
__global__ void linear16_kernel(const float* __restrict__ X, const float* __restrict__ W,
                                const float* __restrict__ b, float* __restrict__ Y, int N) {
    int tid = blockIdx.x * blockDim.x + threadIdx.x;
    int row = tid >> 4;
    int j = tid & 15;
    if (row >= N) return;
    float acc = b ? b[j] : 0.0f;
    const float* xr = X + (size_t)row * EMB;
#pragma unroll
    for (int k = 0; k < EMB; ++k) acc = fmaf(xr[k], W[k * EMB + j], acc);
    Y[(size_t)row * EMB + j] = acc;
}

// ---------------- bucket CSR build ----------------

__global__ void bucket_hist_kernel(const int* __restrict__ ridx, int* __restrict__ bhist,
                                   int E, int NB) {
    __shared__ int h[MAXNB];
    int t = threadIdx.x;
    for (int i = t; i < NB; i += 256) h[i] = 0;
    __syncthreads();
    int idx = blockIdx.x * blockDim.x + t;
    int stride = gridDim.x * blockDim.x;
    for (int e = idx; e < E; e += stride) atomicAdd(&h[ridx[e] >> BSH], 1);
    __syncthreads();
    for (int i = t; i < NB; i += 256) if (h[i]) atomicAdd(&bhist[i], h[i]);
}

__global__ void bucket_scan_kernel(const int* __restrict__ bhist, int* __restrict__ boff,
                                   int* __restrict__ gcur, int NB) {
    __shared__ int sc[1024];
    int t = threadIdx.x;
    int v = (t < NB) ? bhist[t] : 0;
    sc[t] = v;
    __syncthreads();
    for (int d = 1; d < 1024; d <<= 1) {
        int x = (t >= d) ? sc[t - d] : 0;
        __syncthreads();
        sc[t] += x;
        __syncthreads();
    }
    int excl = sc[t] - v;
    if (t < NB) { boff[t] = excl; gcur[t] = excl; }
    if (t == 1023) boff[NB] = sc[1023];
}

// Partition v2: counting-sort the chunk in LDS (int atomics only), then a
// DECOUPLED write loop: thread t writes sorted element t to gadj[bkt]+t --
// coalesced runs, no store depends on an atomic return.
// Record: [f:32][l:24][rl:8].
__launch_bounds__(512)
__global__ void partition_kernel(const int* __restrict__ eidx, const float* __restrict__ ef,
                                 int* __restrict__ gcur, u64* __restrict__ rec, int E, int NB) {
    __shared__ u64 srec[PCHUNK];                 // 64 KB
    __shared__ unsigned short sbkt[PCHUNK];      // 16 KB
    __shared__ int hist[MAXNB];                  // counts -> cursor
    __shared__ int lbase[MAXNB];                 // scan workspace / excl prefix
    __shared__ int gadj[MAXNB];                  // global adjust: respos - lbase
    int t = threadIdx.x;
    long long base = (long long)blockIdx.x * PCHUNK;
    int n = (int)((E - base) < PCHUNK ? (E - base) : PCHUNK);
    const int* ridx = eidx + E;

    for (int i = t; i < NB; i += 512) hist[i] = 0;
    __syncthreads();
    // pass 1: per-bucket counts
    for (int i = t; i < n; i += 512) atomicAdd(&hist[ridx[base + i] >> BSH], 1);
    __syncthreads();
    // inclusive scan over 512 slots (v=0 beyond NB)
    int v = (t < NB) ? hist[t] : 0;
    lbase[t] = v;
    __syncthreads();
    for (int d = 1; d < 512; d <<= 1) {
        int x = (t >= d) ? lbase[t - d] : 0;
        __syncthreads();
        lbase[t] += x;
        __syncthreads();
    }
    int excl = lbase[t] - v;   // exclusive prefix
    __syncthreads();
    lbase[t] = excl;
    if (t < NB) {
        gadj[t] = v ? (atomicAdd(&gcur[t], v) - excl) : 0;
        hist[t] = excl;        // reuse as sort cursor
    }
    __syncthreads();
    // pass 2: counting-sort records into LDS
    for (int i = t; i < n; i += 512) {
        int r = ridx[base + i];
        int b = r >> BSH;
        int l = eidx[base + i];
        float f = ef[base + i];
        int pos = atomicAdd(&hist[b], 1);
        srec[pos] = ((u64)__float_as_uint(f) << 32) | ((u64)(u32)l << BSH) | (u32)(r & (BNODES - 1));
        sbkt[pos] = (unsigned short)b;
    }
    __syncthreads();
    // pass 3: coalesced write-out (consecutive t -> consecutive addresses per run)
    for (int i = t; i < n; i += 512) {
        rec[(long long)gadj[sbkt[i]] + i] = srec[i];
    }
}

// ---------------- gather: one block per 256-node bucket ----------------
// In-block counting sort by local node id (int LDS atomics only), then
// owner-computes: 2 threads per node accumulate in REGISTERS (zero fp atomics),
// combine via one shfl_xor, coalesced float4 store of S.
__launch_bounds__(512)
__global__ void bucket_gather_kernel(const u64* __restrict__ rec, const int* __restrict__ boff,
                                     const u32* __restrict__ Lpk, const u32* __restrict__ Rpk,
                                     const float* __restrict__ We,
                                     float* __restrict__ S, int* __restrict__ deg, int n_right) {
    __shared__ u64 srec[REC_CAP];                        // 40 KB sorted records
    __shared__ int hist[BNODES], sc[BNODES], base_[BNODES], cur[BNODES];
    int b = blockIdx.x;
    int t = threadIdx.x;
    int node0 = b << BSH;
    int start = boff[b], end = boff[b + 1];

    int n = t >> 1, q = t & 1;        // owner: node n (0..255), slice q (0..1)
    int node = node0 + n;
    bool nv = node < n_right;

    float we[16];
#pragma unroll
    for (int j = 0; j < 16; ++j) we[j] = We[j];

    float rv[16];
    if (nv) {
        const uint4* rp = (const uint4*)(Rpk + (size_t)node * 8);
        uint4 ra = rp[0], rb = rp[1];
        u32 w0 = ra.x, w1 = ra.y, w2 = ra.z, w3 = ra.w;
        u32 w4 = rb.x, w5 = rb.y, w6 = rb.z, w7 = rb.w;
        rv[0] = __uint_as_float(w0 << 16); rv[8]  = __uint_as_float(w0 & 0xffff0000u);
        rv[1] = __uint_as_float(w1 << 16); rv[9]  = __uint_as_float(w1 & 0xffff0000u);
        rv[2] = __uint_as_float(w2 << 16); rv[10] = __uint_as_float(w2 & 0xffff0000u);
        rv[3] = __uint_as_float(w3 << 16); rv[11] = __uint_as_float(w3 & 0xffff0000u);
        rv[4] = __uint_as_float(w4 << 16); rv[12] = __uint_as_float(w4 & 0xffff0000u);
        rv[5] = __uint_as_float(w5 << 16); rv[13] = __uint_as_float(w5 & 0xffff0000u);
        rv[6] = __uint_as_float(w6 << 16); rv[14] = __uint_as_float(w6 & 0xffff0000u);
        rv[7] = __uint_as_float(w7 << 16); rv[15] = __uint_as_float(w7 & 0xffff0000u);
    } else {
#pragma unroll
        for (int j = 0; j < 16; ++j) rv[j] = 0.0f;
    }

    float acc[16];
#pragma unroll
    for (int j = 0; j < 16; ++j) acc[j] = 0.0f;
    int dsum = 0;

    for (int tile = start; tile < end; tile += REC_CAP) {
        int m = end - tile; if (m > REC_CAP) m = REC_CAP;
        for (int i = t; i < BNODES; i += 512) hist[i] = 0;
        __syncthreads();
        // pass 1: per-node count (int LDS atomics)
        for (int i = t; i < m; i += 512) {
            u64 rc = rec[tile + i];
            atomicAdd(&hist[(int)(rc & (u32)(BNODES - 1))], 1);
        }
        __syncthreads();
        // exclusive scan over 256 counts
        if (t < BNODES) sc[t] = hist[t];
        __syncthreads();
        for (int d = 1; d < BNODES; d <<= 1) {
            int v = 0;
            if (t < BNODES && t >= d) v = sc[t - d];
            __syncthreads();
            if (t < BNODES && t >= d) sc[t] += v;
            __syncthreads();
        }
        if (t < BNODES) { int e0 = sc[t] - hist[t]; base_[t] = e0; cur[t] = e0; }
        __syncthreads();
        // pass 2: scatter records into sorted LDS positions (int LDS atomics)
        for (int i = t; i < m; i += 512) {
            u64 rc = rec[tile + i];
            int pos = atomicAdd(&cur[(int)(rc & (u32)(BNODES - 1))], 1);
            srec[pos] = rc;
        }
        __syncthreads();
        // owner phase: node n's slice-q thread walks its run, register accumulate
        {
            int c  = nv ? hist[n] : 0;
            int b0 = nv ? base_[n] : 0;
            if (q == 0) dsum += c;
            for (int k = q; k < c; k += 2) {
                u64 rc = srec[b0 + k];
                int l = (int)((rc >> BSH) & 0xFFFFFFu);
                float f = __uint_as_float((u32)(rc >> 32));
                const uint4* lp = (const uint4*)(Lpk + (size_t)l * 8);
                uint4 la = lp[0], lb = lp[1];
                u32 w0 = la.x, w1 = la.y, w2 = la.z, w3 = la.w;
                u32 w4 = lb.x, w5 = lb.y, w6 = lb.z, w7 = lb.w;
#define PAIR(h, lw) { \
                float l0 = __uint_as_float(lw << 16); \
                float l1 = __uint_as_float(lw & 0xffff0000u); \
                acc[h]     += fmaxf(fmaf(f, we[h], l0) + rv[h], 0.0f); \
                acc[h + 8] += fmaxf(fmaf(f, we[h + 8], l1) + rv[h + 8], 0.0f); }
                PAIR(0, w0) PAIR(1, w1) PAIR(2, w2) PAIR(3, w3)
                PAIR(4, w4) PAIR(5, w5) PAIR(6, w6) PAIR(7, w7)
#undef PAIR
            }
        }
        __syncthreads();  // before hist/srec reuse in next tile
    }

    // combine the 2 owner slices (lanes 2n, 2n+1 are in the same wave)
#pragma unroll
    for (int j = 0; j < 16; ++j) acc[j] += __shfl_xor(acc[j], 1, 64);
    if (nv) {
        float4* Op = (float4*)(S + (size_t)node * EMB);
        Op[q * 2]     = make_float4(acc[q * 8],     acc[q * 8 + 1], acc[q * 8 + 2], acc[q * 8 + 3]);
        Op[q * 2 + 1] = make_float4(acc[q * 8 + 4], acc[q * 8 + 5], acc[q * 8 + 6], acc[q * 8 + 7]);
        if (q == 0) deg[node] = dsum;
    }
}

// ---------------- fallback atomic edge kernel (f32 tables) ----------------
__global__ void edge_kernel(const int* __restrict__ eidx, const float* __restrict__ ef,
                            const float* __restrict__ L, const float* __restrict__ R,
                            const float* __restrict__ We, float* __restrict__ S,
                            int* __restrict__ cnt, int E) {
    long long tid = (long long)blockIdx.x * blockDim.x + threadIdx.x;
    int e = (int)(tid >> 4);
    int j = (int)(tid & 15);
    if (e >= E) return;
    int l = eidx[e];
    int r = eidx[E + e];
    float v = L[(size_t)l * EMB + j] + ef[e] * We[j] + R[(size_t)r * EMB + j];
    v = fmaxf(v, 0.0f);
    unsafeAtomicAdd(&S[(size_t)r * EMB + j], v);
    if (j == 0) atomicAdd(&cnt[r], 1);
}

// ---------------- per-node epilogue ----------------
__global__ void final_kernel(const float* __restrict__ S, const int* __restrict__ deg,
                             const float* __restrict__ rf,
                             const float* __restrict__ Wf, const float* __restrict__ bf,
                             const float* __restrict__ Wp, const float* __restrict__ bp,
                             const float* __restrict__ Wo1, const float* __restrict__ bo1,
                             const float* __restrict__ Wo2, const float* __restrict__ bo2,
                             float* __restrict__ out, int N) {
    __shared__ float sWf[256], sWp[256], sWo1[512], sWo2[256];
    __shared__ float sb[64];
    int t = threadIdx.x;
    for (int i = t; i < 256; i += 256) { sWf[i] = Wf[i]; sWp[i] = Wp[i]; sWo2[i] = Wo2[i]; }
    for (int i = t; i < 512; i += 256) sWo1[i] = Wo1[i];
    if (t < 16) { sb[t] = bf[t]; sb[16 + t] = bp[t]; sb[32 + t] = bo1[t]; sb[48 + t] = bo2[t]; }
    __syncthreads();

    int r = blockIdx.x * blockDim.x + t;
    if (r >= N) return;

    float s[16], x[16], y[16], rv[16], z[16], o[16];
    const float4* Sp = (const float4*)(S + (size_t)r * EMB);
    const float4* Rp = (const float4*)(rf + (size_t)r * EMB);
#pragma unroll
    for (int k = 0; k < 4; ++k) {
        float4 v = Sp[k];
        s[4 * k] = v.x; s[4 * k + 1] = v.y; s[4 * k + 2] = v.z; s[4 * k + 3] = v.w;
        float4 w = Rp[k];
        rv[4 * k] = w.x; rv[4 * k + 1] = w.y; rv[4 * k + 2] = w.z; rv[4 * k + 3] = w.w;
    }
    float c = (float)deg[r];

#pragma unroll
    for (int j = 0; j < 16; ++j) {
        float a = c * sb[j];
#pragma unroll
        for (int k = 0; k < 16; ++k) a = fmaf(s[k], sWf[k * 16 + j], a);
        x[j] = fmaxf(a, 0.0f);
    }
#pragma unroll
    for (int j = 0; j < 16; ++j) {
        float a = sb[16 + j];
#pragma unroll
        for (int k = 0; k < 16; ++k) a = fmaf(x[k], sWp[k * 16 + j], a);
        y[j] = a;
    }
#pragma unroll
    for (int j = 0; j < 16; ++j) {
        float a = sb[32 + j];
#pragma unroll
        for (int k = 0; k < 16; ++k) a = fmaf(y[k], sWo1[k * 16 + j], a);
#pragma unroll
        for (int k = 0; k < 16; ++k) a = fmaf(rv[k], sWo1[(16 + k) * 16 + j], a);
        z[j] = fmaxf(a, 0.0f);
    }
#pragma unroll
    for (int j = 0; j < 16; ++j) {
        float a = sb[48 + j];
#pragma unroll
        for (int k = 0; k < 16; ++k) a = fmaf(z[k], sWo2[k * 16 + j], a);
        o[j] = a;
    }
    float4* Op = (float4*)(out + (size_t)r * EMB);
#pragma unroll
    for (int k = 0; k < 4; ++k)
        Op[k] = make_float4(o[4 * k], o[4 * k + 1], o[4 * k + 2], o[4 * k + 3]);
}

extern "C" void kernel_launch(void* const* d_in, const int* in_sizes, int n_in,
                              void* d_out, int out_size, void* d_ws, size_t ws_size,
                              hipStream_t stream) {
    const float* lf     = (const float*)d_in[0];
    const int*   eidx   = (const int*)d_in[1];
    const float* ef     = (const float*)d_in[2];
    const float* rf     = (const float*)d_in[3];
    const float* W_left = (const float*)d_in[4];
    const float* b_left = (const float*)d_in[5];
    const float* W_edge = (const float*)d_in[6];
    const float* W_right= (const float*)d_in[7];
    const float* W_final= (const float*)d_in[8];
    const float* b_final= (const float*)d_in[9];
    const float* W_post = (const float*)d_in[10];
    const float* b_post = (const float*)d_in[11];
    const float* W_out1 = (const float*)d_in[12];
    const float* b_out1 = (const float*)d_in[13];
    const float* W_out2 = (const float*)d_in[14];
    const float* b_out2 = (const float*)d_in[15];

    int n_left  = in_sizes[0] / EMB;
    int E       = in_sizes[2];
    int n_right = in_sizes[3] / EMB;
    float* out = (float*)d_out;

    int NB = (n_right + BNODES - 1) >> BSH;

    size_t need = (size_t)E * 8
                + ((size_t)n_left + (size_t)n_right) * 8 * 4   // Lpk, Rpk
                + (size_t)n_right * EMB * 4                    // S
                + (size_t)n_right * 4                          // deg
                + (size_t)(3 * MAXNB + 2) * 4;

    if (ws_size >= need && NB <= MAXNB) {
        u64* rec   = (u64*)d_ws;
        u32* Lpk   = (u32*)(rec + (size_t)E);
        u32* Rpk   = Lpk + (size_t)n_left * 8;
        float* S   = (float*)(Rpk + (size_t)n_right * 8);
        int* deg   = (int*)(S + (size_t)n_right * EMB);
        int* bhist = deg + n_right;
        int* boff  = bhist + MAXNB;      // NB+1 entries
        int* gcur  = boff + MAXNB + 1;

        zero_i32<<<(NB + 255) / 256, 256, 0, stream>>>(bhist, NB);
        linear16_pack_kernel<<<(n_left * 8 + 255) / 256, 256, 0, stream>>>(lf, W_left, b_left, Lpk, n_left);
        linear16_pack_kernel<<<(n_right * 8 + 255) / 256, 256, 0, stream>>>(rf, W_right, nullptr, Rpk, n_right);

        bucket_hist_kernel<<<512, 256, 0, stream>>>(eidx + E, bhist, E, NB);
        bucket_scan_kernel<<<1, 1024, 0, stream>>>(bhist, boff, gcur, NB);

        int nchunks = (E + PCHUNK - 1) / PCHUNK;
        partition_kernel<<<nchunks, 512, 0, stream>>>(eidx, ef, gcur, rec, E, NB);

        bucket_gather_kernel<<<NB, 512, 0, stream>>>(rec, boff, Lpk, Rpk, W_edge, S, deg, n_right);

        final_kernel<<<(n_right + 255) / 256, 256, 0, stream>>>(S, deg, rf,
            W_final, b_final, W_post, b_post, W_out1, b_out1, W_out2, b_out2, out, n_right);
    } else {
        float* L   = (float*)d_ws;
        float* R   = L + (size_t)n_left * EMB;
        float* S   = R + (size_t)n_right * EMB;
        int*   cnt = (int*)(S + (size_t)n_right * EMB);

        zero_f32<<<2048, 256, 0, stream>>>(S, (size_t)n_right * EMB);
        zero_i32<<<(n_right + 255) / 256, 256, 0, stream>>>(cnt, n_right);

        linear16_kernel<<<(n_left * EMB + 255) / 256, 256, 0, stream>>>(lf, W_left, b_left, L, n_left);
        linear16_kernel<<<(n_right * EMB + 255) / 256, 256, 0, stream>>>(rf, W_right, nullptr, R, n_right);

        long long ethreads = (long long)E * EMB;
        edge_kernel<<<(unsigned)((ethreads + 255) / 256), 256, 0, stream>>>(eidx, ef, L, R, W_edge, S, cnt, E);

        final_kernel<<<(n_right + 255) / 256, 256, 0, stream>>>(S, cnt, rf,
            W_final, b_final, W_post, b_post, W_out1, b_out1, W_out2, b_out2, out, n_right);
    }
}

// Round 11
// 99.820 us; speedup vs baseline: 1.6531x; 1.2849x over previous
//
#include <hip/hip_runtime.h>

#define EMB 16
#define BSH 8                 // 256 right-nodes per bucket
#define BNODES 256
#define MAXNB 512
#define PCHUNK 8192           // edges per chunk-sort block
#define MAXCHUNKS 1024
#define REC_CAP 4096          // records per gather LDS tile (32 KB)
#define RPT 8                 // REC_CAP / 512
typedef unsigned int u32;
typedef unsigned long long u64;

__global__ void zero_f32(float* __restrict__ p, size_t n) {
    size_t i = (size_t)blockIdx.x * blockDim.x + threadIdx.x;
    size_t stride = (size_t)gridDim.x * blockDim.x;
    for (; i < n; i += stride) p[i] = 0.0f;
}

__global__ void zero_i32(int* __restrict__ p, int n) {
    int i = blockIdx.x * blockDim.x + threadIdx.x;
    if (i < n) p[i] = 0;
}

__device__ __forceinline__ u32 bf16bits_rne(float x) {
    u32 u = __float_as_uint(x);
    return (u + 0x7fffu + ((u >> 16) & 1u)) >> 16;
}

// Packed bf16 linear: Y[row*8+h] = pack(bf16(row@W[:,h+8]+b), bf16(row@W[:,h]+b))
__global__ void linear16_pack_kernel(const float* __restrict__ X, const float* __restrict__ W,
                                     const float* __restrict__ b, u32* __restrict__ Y, int N) {
    int tid = blockIdx.x * blockDim.x + threadIdx.x;
    int row = tid >> 3;
    int h = tid & 7;
    if (row >= N) return;
    float a0 = b ? b[h] : 0.0f;
    float a1 = b ? b[h + 8] : 0.0f;
    const float* xr = X + (size_t)row * EMB;
#pragma unroll
    for (int k = 0; k < EMB; ++k) {
        float xv = xr[k];
        a0 = fmaf(xv, W[k * EMB + h], a0);
        a1 = fmaf(xv, W[k * EMB + h + 8], a1);
    }
    Y[(size_t)row * 8 + h] = (bf16bits_rne(a1) << 16) | bf16bits_rne(a0);
}

// Plain f32 linear (fallback path)
__global__ void linear16_kernel(const float* __restrict__ X, const float* __restrict__ W,
                                const float* __restrict__ b, float* __restrict__ Y, int N) {
    int tid = blockIdx.x * blockDim.x + threadIdx.x;
    int row = tid >> 4;
    int j = tid & 15;
    if (row >= N) return;
    float acc = b ? b[j] : 0.0f;
    const float* xr = X + (size_t)row * EMB;
#pragma unroll
    for (int k = 0; k < EMB; ++k) acc = fmaf(xr[k], W[k * EMB + j], acc);
    Y[(size_t)row * EMB + j] = acc;
}

// ---------------- chunk-sort: no global atomics, fully coalesced writes -------
// Chunk c sorts its PCHUNK edges by bucket in LDS and writes them to
// rec[c*PCHUNK ..] (write order == sorted order). Emits cnt[c][b] and
// cbase[c][b] (within-chunk run starts). Record: [f:32][l:24][rl:8].
__launch_bounds__(512)
__global__ void chunk_sort_kernel(const int* __restrict__ eidx, const float* __restrict__ ef,
                                  u64* __restrict__ rec, int* __restrict__ cntM,
                                  int* __restrict__ cbaseM, int E, int NB) {
    __shared__ u64 srec[PCHUNK];   // 64 KB
    __shared__ int hist[MAXNB];    // counts -> cursors
    __shared__ int sc[512];        // scan workspace
    int t = threadIdx.x;
    int c = blockIdx.x;
    long long base = (long long)c * PCHUNK;
    int n = (int)(((long long)E - base) < PCHUNK ? ((long long)E - base) : PCHUNK);
    const int* ridx = eidx + E;

    for (int i = t; i < NB; i += 512) hist[i] = 0;
    __syncthreads();
    for (int i = t; i < n; i += 512) atomicAdd(&hist[ridx[base + i] >> BSH], 1);
    __syncthreads();
    int v = (t < NB) ? hist[t] : 0;
    sc[t] = v;
    __syncthreads();
    for (int d = 1; d < 512; d <<= 1) {
        int x = (t >= d) ? sc[t - d] : 0;
        __syncthreads();
        sc[t] += x;
        __syncthreads();
    }
    int ex = sc[t] - v;   // exclusive prefix
    if (t < NB) {
        cntM[(size_t)c * NB + t] = v;
        cbaseM[(size_t)c * NB + t] = ex;
        hist[t] = ex;      // reuse as sort cursor
    }
    __syncthreads();
    for (int i = t; i < n; i += 512) {
        int r = ridx[base + i];
        int bb = r >> BSH;
        int l = eidx[base + i];
        float f = ef[base + i];
        int pos = atomicAdd(&hist[bb], 1);
        srec[pos] = ((u64)__float_as_uint(f) << 32) | ((u64)(u32)l << BSH) | (u32)(r & (BNODES - 1));
    }
    __syncthreads();
    for (int i = t; i < n; i += 512) rec[base + i] = srec[i];
}

// ---------------- gather: one block per 256-node bucket ----------------
// Builds LDS prefix over its per-chunk run lengths; loads records via binary
// search into REGISTERS (rec read once); in-LDS counting sort by node; owner
// threads (2/node) accumulate in registers; zero fp atomics anywhere.
__launch_bounds__(512)
__global__ void bucket_gather_kernel(const u64* __restrict__ rec, const int* __restrict__ cntM,
                                     const int* __restrict__ cbaseM,
                                     const u32* __restrict__ Lpk, const u32* __restrict__ Rpk,
                                     const float* __restrict__ We,
                                     float* __restrict__ S, int* __restrict__ deg,
                                     int n_right, int NB, int nchunks) {
    __shared__ u64 srec[REC_CAP];                 // 32 KB
    __shared__ int runsum[MAXCHUNKS + 1];         // global start of each chunk's run
    __shared__ int rbase[MAXCHUNKS];              // rec index of each run start
    __shared__ int ssc[512];
    __shared__ int hist[BNODES], scn[BNODES], base_[BNODES], cur[BNODES];
    int b = blockIdx.x;
    int t = threadIdx.x;
    int node0 = b << BSH;

    // prefix over run lengths (2 chunks per thread)
    int c0 = 2 * t, c1 = 2 * t + 1;
    int len0 = (c0 < nchunks) ? cntM[(size_t)c0 * NB + b] : 0;
    int len1 = (c1 < nchunks) ? cntM[(size_t)c1 * NB + b] : 0;
    ssc[t] = len0 + len1;
    __syncthreads();
    for (int d = 1; d < 512; d <<= 1) {
        int x = (t >= d) ? ssc[t - d] : 0;
        __syncthreads();
        ssc[t] += x;
        __syncthreads();
    }
    int pexcl = ssc[t] - (len0 + len1);
    if (c0 < nchunks) { runsum[c0] = pexcl;        rbase[c0] = c0 * PCHUNK + cbaseM[(size_t)c0 * NB + b]; }
    if (c1 < nchunks) { runsum[c1] = pexcl + len0; rbase[c1] = c1 * PCHUNK + cbaseM[(size_t)c1 * NB + b]; }
    if (t == 511) runsum[nchunks] = ssc[511];
    __syncthreads();
    int total = runsum[nchunks];

    int n = t >> 1, q = t & 1;        // owner: node n (0..255), slice q (0..1)
    int node = node0 + n;
    bool nv = node < n_right;

    float we[16];
#pragma unroll
    for (int j = 0; j < 16; ++j) we[j] = We[j];

    float rv[16];
    if (nv) {
        const uint4* rp = (const uint4*)(Rpk + (size_t)node * 8);
        uint4 ra = rp[0], rb = rp[1];
        u32 w0 = ra.x, w1 = ra.y, w2 = ra.z, w3 = ra.w;
        u32 w4 = rb.x, w5 = rb.y, w6 = rb.z, w7 = rb.w;
        rv[0] = __uint_as_float(w0 << 16); rv[8]  = __uint_as_float(w0 & 0xffff0000u);
        rv[1] = __uint_as_float(w1 << 16); rv[9]  = __uint_as_float(w1 & 0xffff0000u);
        rv[2] = __uint_as_float(w2 << 16); rv[10] = __uint_as_float(w2 & 0xffff0000u);
        rv[3] = __uint_as_float(w3 << 16); rv[11] = __uint_as_float(w3 & 0xffff0000u);
        rv[4] = __uint_as_float(w4 << 16); rv[12] = __uint_as_float(w4 & 0xffff0000u);
        rv[5] = __uint_as_float(w5 << 16); rv[13] = __uint_as_float(w5 & 0xffff0000u);
        rv[6] = __uint_as_float(w6 << 16); rv[14] = __uint_as_float(w6 & 0xffff0000u);
        rv[7] = __uint_as_float(w7 << 16); rv[15] = __uint_as_float(w7 & 0xffff0000u);
    } else {
#pragma unroll
        for (int j = 0; j < 16; ++j) rv[j] = 0.0f;
    }

    float acc[16];
#pragma unroll
    for (int j = 0; j < 16; ++j) acc[j] = 0.0f;
    int dsum = 0;

    for (int tile0 = 0; tile0 < total; tile0 += REC_CAP) {
        int m = total - tile0; if (m > REC_CAP) m = REC_CAP;
        u64 rcl[RPT];
        for (int i = t; i < BNODES; i += 512) hist[i] = 0;
        __syncthreads();
        // load into registers via binary search over runsum (rec read ONCE)
#pragma unroll
        for (int k = 0; k < RPT; ++k) {
            int i = t + k * 512;
            rcl[k] = 0;
            if (i < m) {
                int g = tile0 + i;
                int lo = 0, hi = nchunks - 1;
                while (lo < hi) { int mid = (lo + hi + 1) >> 1; if (runsum[mid] <= g) lo = mid; else hi = mid - 1; }
                rcl[k] = rec[(size_t)rbase[lo] + (g - runsum[lo])];
            }
        }
        // count (int LDS atomics)
#pragma unroll
        for (int k = 0; k < RPT; ++k) {
            int i = t + k * 512;
            if (i < m) atomicAdd(&hist[(int)(rcl[k] & (u32)(BNODES - 1))], 1);
        }
        __syncthreads();
        // exclusive scan over 256 counts
        if (t < BNODES) scn[t] = hist[t];
        __syncthreads();
        for (int d = 1; d < BNODES; d <<= 1) {
            int v2 = 0;
            if (t < BNODES && t >= d) v2 = scn[t - d];
            __syncthreads();
            if (t < BNODES && t >= d) scn[t] += v2;
            __syncthreads();
        }
        if (t < BNODES) { int e0 = scn[t] - hist[t]; base_[t] = e0; cur[t] = e0; }
        __syncthreads();
        // scatter from registers into node-sorted LDS
#pragma unroll
        for (int k = 0; k < RPT; ++k) {
            int i = t + k * 512;
            if (i < m) {
                int pos = atomicAdd(&cur[(int)(rcl[k] & (u32)(BNODES - 1))], 1);
                srec[pos] = rcl[k];
            }
        }
        __syncthreads();
        // owner phase: node n's slice-q thread walks its run, register accumulate
        {
            int cc = nv ? hist[n] : 0;
            int b0 = nv ? base_[n] : 0;
            if (q == 0) dsum += cc;
            for (int k = q; k < cc; k += 2) {
                u64 rc = srec[b0 + k];
                int l = (int)((rc >> BSH) & 0xFFFFFFu);
                float f = __uint_as_float((u32)(rc >> 32));
                const uint4* lp = (const uint4*)(Lpk + (size_t)l * 8);
                uint4 la = lp[0], lb = lp[1];
                u32 w0 = la.x, w1 = la.y, w2 = la.z, w3 = la.w;
                u32 w4 = lb.x, w5 = lb.y, w6 = lb.z, w7 = lb.w;
#define PAIR(h, lw) { \
                float l0 = __uint_as_float(lw << 16); \
                float l1 = __uint_as_float(lw & 0xffff0000u); \
                acc[h]     += fmaxf(fmaf(f, we[h], l0) + rv[h], 0.0f); \
                acc[h + 8] += fmaxf(fmaf(f, we[h + 8], l1) + rv[h + 8], 0.0f); }
                PAIR(0, w0) PAIR(1, w1) PAIR(2, w2) PAIR(3, w3)
                PAIR(4, w4) PAIR(5, w5) PAIR(6, w6) PAIR(7, w7)
#undef PAIR
            }
        }
        __syncthreads();  // before hist/srec reuse in next tile
    }

    // combine the 2 owner slices (lanes 2n, 2n+1 are in the same wave)
#pragma unroll
    for (int j = 0; j < 16; ++j) acc[j] += __shfl_xor(acc[j], 1, 64);
    if (nv) {
        float4* Op = (float4*)(S + (size_t)node * EMB);
        Op[q * 2]     = make_float4(acc[q * 8],     acc[q * 8 + 1], acc[q * 8 + 2], acc[q * 8 + 3]);
        Op[q * 2 + 1] = make_float4(acc[q * 8 + 4], acc[q * 8 + 5], acc[q * 8 + 6], acc[q * 8 + 7]);
        if (q == 0) deg[node] = dsum;
    }
}

// ---------------- fallback atomic edge kernel (f32 tables) ----------------
__global__ void edge_kernel(const int* __restrict__ eidx, const float* __restrict__ ef,
                            const float* __restrict__ L, const float* __restrict__ R,
                            const float* __restrict__ We, float* __restrict__ S,
                            int* __restrict__ cnt, int E) {
    long long tid = (long long)blockIdx.x * blockDim.x + threadIdx.x;
    int e = (int)(tid >> 4);
    int j = (int)(tid & 15);
    if (e >= E) return;
    int l = eidx[e];
    int r = eidx[E + e];
    float v = L[(size_t)l * EMB + j] + ef[e] * We[j] + R[(size_t)r * EMB + j];
    v = fmaxf(v, 0.0f);
    unsafeAtomicAdd(&S[(size_t)r * EMB + j], v);
    if (j == 0) atomicAdd(&cnt[r], 1);
}

// ---------------- per-node epilogue ----------------
__global__ void final_kernel(const float* __restrict__ S, const int* __restrict__ deg,
                             const float* __restrict__ rf,
                             const float* __restrict__ Wf, const float* __restrict__ bf,
                             const float* __restrict__ Wp, const float* __restrict__ bp,
                             const float* __restrict__ Wo1, const float* __restrict__ bo1,
                             const float* __restrict__ Wo2, const float* __restrict__ bo2,
                             float* __restrict__ out, int N) {
    __shared__ float sWf[256], sWp[256], sWo1[512], sWo2[256];
    __shared__ float sb[64];
    int t = threadIdx.x;
    for (int i = t; i < 256; i += 256) { sWf[i] = Wf[i]; sWp[i] = Wp[i]; sWo2[i] = Wo2[i]; }
    for (int i = t; i < 512; i += 256) sWo1[i] = Wo1[i];
    if (t < 16) { sb[t] = bf[t]; sb[16 + t] = bp[t]; sb[32 + t] = bo1[t]; sb[48 + t] = bo2[t]; }
    __syncthreads();

    int r = blockIdx.x * blockDim.x + t;
    if (r >= N) return;

    float s[16], x[16], y[16], rv[16], z[16], o[16];
    const float4* Sp = (const float4*)(S + (size_t)r * EMB);
    const float4* Rp = (const float4*)(rf + (size_t)r * EMB);
#pragma unroll
    for (int k = 0; k < 4; ++k) {
        float4 v = Sp[k];
        s[4 * k] = v.x; s[4 * k + 1] = v.y; s[4 * k + 2] = v.z; s[4 * k + 3] = v.w;
        float4 w = Rp[k];
        rv[4 * k] = w.x; rv[4 * k + 1] = w.y; rv[4 * k + 2] = w.z; rv[4 * k + 3] = w.w;
    }
    float c = (float)deg[r];

#pragma unroll
    for (int j = 0; j < 16; ++j) {
        float a = c * sb[j];
#pragma unroll
        for (int k = 0; k < 16; ++k) a = fmaf(s[k], sWf[k * 16 + j], a);
        x[j] = fmaxf(a, 0.0f);
    }
#pragma unroll
    for (int j = 0; j < 16; ++j) {
        float a = sb[16 + j];
#pragma unroll
        for (int k = 0; k < 16; ++k) a = fmaf(x[k], sWp[k * 16 + j], a);
        y[j] = a;
    }
#pragma unroll
    for (int j = 0; j < 16; ++j) {
        float a = sb[32 + j];
#pragma unroll
        for (int k = 0; k < 16; ++k) a = fmaf(y[k], sWo1[k * 16 + j], a);
#pragma unroll
        for (int k = 0; k < 16; ++k) a = fmaf(rv[k], sWo1[(16 + k) * 16 + j], a);
        z[j] = fmaxf(a, 0.0f);
    }
#pragma unroll
    for (int j = 0; j < 16; ++j) {
        float a = sb[48 + j];
#pragma unroll
        for (int k = 0; k < 16; ++k) a = fmaf(z[k], sWo2[k * 16 + j], a);
        o[j] = a;
    }
    float4* Op = (float4*)(out + (size_t)r * EMB);
#pragma unroll
    for (int k = 0; k < 4; ++k)
        Op[k] = make_float4(o[4 * k], o[4 * k + 1], o[4 * k + 2], o[4 * k + 3]);
}

extern "C" void kernel_launch(void* const* d_in, const int* in_sizes, int n_in,
                              void* d_out, int out_size, void* d_ws, size_t ws_size,
                              hipStream_t stream) {
    const float* lf     = (const float*)d_in[0];
    const int*   eidx   = (const int*)d_in[1];
    const float* ef     = (const float*)d_in[2];
    const float* rf     = (const float*)d_in[3];
    const float* W_left = (const float*)d_in[4];
    const float* b_left = (const float*)d_in[5];
    const float* W_edge = (const float*)d_in[6];
    const float* W_right= (const float*)d_in[7];
    const float* W_final= (const float*)d_in[8];
    const float* b_final= (const float*)d_in[9];
    const float* W_post = (const float*)d_in[10];
    const float* b_post = (const float*)d_in[11];
    const float* W_out1 = (const float*)d_in[12];
    const float* b_out1 = (const float*)d_in[13];
    const float* W_out2 = (const float*)d_in[14];
    const float* b_out2 = (const float*)d_in[15];

    int n_left  = in_sizes[0] / EMB;
    int E       = in_sizes[2];
    int n_right = in_sizes[3] / EMB;
    float* out = (float*)d_out;

    int NB = (n_right + BNODES - 1) >> BSH;
    int nchunks = (E + PCHUNK - 1) / PCHUNK;

    size_t need = (size_t)E * 8                        // rec
                + (size_t)nchunks * NB * 8             // cntM + cbaseM
                + ((size_t)n_left + n_right) * 32      // Lpk, Rpk
                + (size_t)n_right * EMB * 4            // S
                + (size_t)n_right * 4;                 // deg

    if (ws_size >= need && NB <= MAXNB && nchunks <= MAXCHUNKS) {
        u64* rec    = (u64*)d_ws;
        int* cntM   = (int*)(rec + (size_t)E);
        int* cbaseM = cntM + (size_t)nchunks * NB;
        u32* Lpk    = (u32*)(cbaseM + (size_t)nchunks * NB);
        u32* Rpk    = Lpk + (size_t)n_left * 8;
        float* S    = (float*)(Rpk + (size_t)n_right * 8);
        int* deg    = (int*)(S + (size_t)n_right * EMB);

        linear16_pack_kernel<<<(n_left * 8 + 255) / 256, 256, 0, stream>>>(lf, W_left, b_left, Lpk, n_left);
        linear16_pack_kernel<<<(n_right * 8 + 255) / 256, 256, 0, stream>>>(rf, W_right, nullptr, Rpk, n_right);

        chunk_sort_kernel<<<nchunks, 512, 0, stream>>>(eidx, ef, rec, cntM, cbaseM, E, NB);

        bucket_gather_kernel<<<NB, 512, 0, stream>>>(rec, cntM, cbaseM, Lpk, Rpk, W_edge,
                                                     S, deg, n_right, NB, nchunks);

        final_kernel<<<(n_right + 255) / 256, 256, 0, stream>>>(S, deg, rf,
            W_final, b_final, W_post, b_post, W_out1, b_out1, W_out2, b_out2, out, n_right);
    } else {
        float* L   = (float*)d_ws;
        float* R   = L + (size_t)n_left * EMB;
        float* S   = R + (size_t)n_right * EMB;
        int*   cnt = (int*)(S + (size_t)n_right * EMB);

        zero_f32<<<2048, 256, 0, stream>>>(S, (size_t)n_right * EMB);
        zero_i32<<<(n_right + 255) / 256, 256, 0, stream>>>(cnt, n_right);

        linear16_kernel<<<(n_left * EMB + 255) / 256, 256, 0, stream>>>(lf, W_left, b_left, L, n_left);
        linear16_kernel<<<(n_right * EMB + 255) / 256, 256, 0, stream>>>(rf, W_right, nullptr, R, n_right);

        long long ethreads = (long long)E * EMB;
        edge_kernel<<<(unsigned)((ethreads + 255) / 256), 256, 0, stream>>>(eidx, ef, L, R, W_edge, S, cnt, E);

        final_kernel<<<(n_right + 255) / 256, 256, 0, stream>>>(S, cnt, rf,
            W_final, b_final, W_post, b_post, W_out1, b_out1, W_out2, b_out2, out, n_right);
    }
}